// Round 1
// baseline (674.698 us; speedup 1.0000x reference)
//
#include <hip/hip_runtime.h>
#include <cstdint>
#include <cstddef>

// MI355X / gfx950. bf16 MFMA implementation of ConditionalCrossAttention.
// score = (qc+qp)|(qc+qp+qs)  dot  kc|kp   (algebraic refold of the concat heads)
// ws layout: K64[128][4096][64] bf16 | V32[128][4096][32] bf16 |
//            Q64[128][320][64] bf16  | Obf[16][300][256] bf16   (~104 MiB)

typedef float  f4  __attribute__((ext_vector_type(4)));
typedef __bf16 b8v __attribute__((ext_vector_type(8)));

#define MFMA_BF16(a, b, c) __builtin_amdgcn_mfma_f32_16x16x32_bf16((a), (b), (c), 0, 0, 0)

// ---------------------------------------------------------------------------
// Kernel A: key-side fused linears. 3 GEMMs: kc = key@W_kc^T, kp = key_pos@W_kp^T,
// v = value@W_v^T. M = L*B = 65536 (row r = l*16 + b), N = 256, K = 256.
// Block: BM=256 x BN=128, 4 waves (each wave 64 rows x 128 cols, rt=4, ct=8).
// Weights staged in LDS (bf16); A fragments converted fp32->bf16 from global.
__global__ __launch_bounds__(256) void key_side_gemm(
    const float* __restrict__ key, const float* __restrict__ key_pos,
    const float* __restrict__ value,
    const float* __restrict__ W_kc, const float* __restrict__ b_kc,
    const float* __restrict__ W_kp, const float* __restrict__ b_kp,
    const float* __restrict__ W_v,  const float* __restrict__ b_v,
    __bf16* __restrict__ K64, __bf16* __restrict__ V32)
{
  __shared__ __bf16 Ws[128][72];   // +8 bf16 pad -> 2-way-free LDS banks
  const int tid  = threadIdx.x;
  const int wave = tid >> 6, lane = tid & 63;
  const int lrow = lane & 15, quad = lane >> 4;
  const int n0 = blockIdx.x * 128;   // 0 / 128
  const int r0 = blockIdx.y * 256;   // M tile

  const float* Xp_[3] = {key, key_pos, value};
  const float* Wp_[3] = {W_kc, W_kp, W_v};
  const float* Bp_[3] = {b_kc, b_kp, b_v};

  for (int p = 0; p < 3; ++p) {
    const float* __restrict__ X = Xp_[p];
    const float* __restrict__ W = Wp_[p];
    f4 acc[4][8];
#pragma unroll
    for (int i = 0; i < 4; ++i)
#pragma unroll
      for (int j = 0; j < 8; ++j) acc[i][j] = f4{0.f, 0.f, 0.f, 0.f};

    for (int kc0 = 0; kc0 < 256; kc0 += 64) {
      // stage W[n0..n0+128)[kc0..kc0+64) as bf16
#pragma unroll
      for (int it = 0; it < 8; ++it) {
        int idx = it * 256 + tid;
        int row = idx >> 4, c4 = idx & 15;
        float4 w = *(const float4*)(W + (size_t)(n0 + row) * 256 + kc0 + c4 * 4);
        __bf16* dp = &Ws[row][c4 * 4];
        dp[0] = (__bf16)w.x; dp[1] = (__bf16)w.y; dp[2] = (__bf16)w.z; dp[3] = (__bf16)w.w;
      }
      __syncthreads();
#pragma unroll
      for (int kk = 0; kk < 64; kk += 32) {
        b8v a[4];
#pragma unroll
        for (int rt = 0; rt < 4; ++rt) {
          const float* xp = X + (size_t)(r0 + wave * 64 + rt * 16 + lrow) * 256 + kc0 + kk + quad * 8;
          float4 x0 = *(const float4*)xp;
          float4 x1 = *(const float4*)(xp + 4);
          b8v t;
          t[0] = (__bf16)x0.x; t[1] = (__bf16)x0.y; t[2] = (__bf16)x0.z; t[3] = (__bf16)x0.w;
          t[4] = (__bf16)x1.x; t[5] = (__bf16)x1.y; t[6] = (__bf16)x1.z; t[7] = (__bf16)x1.w;
          a[rt] = t;
        }
#pragma unroll
        for (int ct = 0; ct < 8; ++ct) {
          b8v bf = *(const b8v*)&Ws[ct * 16 + lrow][kk + quad * 8];
#pragma unroll
          for (int rt = 0; rt < 4; ++rt)
            acc[rt][ct] = MFMA_BF16(a[rt], bf, acc[rt][ct]);
        }
      }
      __syncthreads();
    }
    // epilogue: + bias, scatter to [bh][l][64] / [bh][l][32]
    const float* bias = Bp_[p];
#pragma unroll
    for (int ct = 0; ct < 8; ++ct) {
      int col = n0 + ct * 16 + lrow;
      float bv = bias[col];
      int h = col >> 5, d = col & 31;
#pragma unroll
      for (int rt = 0; rt < 4; ++rt) {
#pragma unroll
        for (int r = 0; r < 4; ++r) {
          int row = r0 + wave * 64 + rt * 16 + quad * 4 + r;
          int l = row >> 4, bb = row & 15;
          float val = acc[rt][ct][r] + bv;
          if (p == 2) {
            V32[((size_t)(bb * 8 + h) * 4096 + l) * 32 + d] = (__bf16)val;
          } else {
            K64[((size_t)(bb * 8 + h) * 4096 + l) * 64 + (p == 1 ? 32 : 0) + d] = (__bf16)val;
          }
        }
      }
    }
  }
}

// ---------------------------------------------------------------------------
// Kernel B: query-side. One accumulator, phased:
//   phase 1 (K=512 concat): T = query@W_qc^T + query_pos@W_qp^T  -> write half 0 (T+biases)*scale
//   phase 2 (K=256):        T += query_sine@W_qs^T               -> write half 1 (T+biases)*scale
// M = 4800 (row = n*16+b), BM=64, BN=256, scale = 1/8 folded into Q.
__global__ __launch_bounds__(256) void query_side_gemm(
    const float* __restrict__ query, const float* __restrict__ query_pos,
    const float* __restrict__ query_sine,
    const float* __restrict__ W_qc, const float* __restrict__ b_qc,
    const float* __restrict__ W_qp, const float* __restrict__ b_qp,
    const float* __restrict__ W_qs, const float* __restrict__ b_qs,
    __bf16* __restrict__ Q64)
{
  __shared__ __bf16 Ws[256][72];
  const int tid  = threadIdx.x;
  const int wave = tid >> 6, lane = tid & 63;
  const int lrow = lane & 15, quad = lane >> 4;
  const int r0 = blockIdx.x * 64;

  f4 acc[16];
#pragma unroll
  for (int i = 0; i < 16; ++i) acc[i] = f4{0.f, 0.f, 0.f, 0.f};

  for (int kc = 0; kc < 768; kc += 64) {
    const float* X; const float* W;
    if (kc < 256)      { X = query;      W = W_qc; }
    else if (kc < 512) { X = query_pos;  W = W_qp; }
    else               { X = query_sine; W = W_qs; }
    const int ko = kc & 255;
#pragma unroll
    for (int it = 0; it < 16; ++it) {
      int idx = it * 256 + tid;
      int row = idx >> 4, c4 = idx & 15;
      float4 w = *(const float4*)(W + (size_t)row * 256 + ko + c4 * 4);
      __bf16* dp = &Ws[row][c4 * 4];
      dp[0] = (__bf16)w.x; dp[1] = (__bf16)w.y; dp[2] = (__bf16)w.z; dp[3] = (__bf16)w.w;
    }
    __syncthreads();
#pragma unroll
    for (int kk = 0; kk < 64; kk += 32) {
      const float* xp = X + (size_t)(r0 + wave * 16 + lrow) * 256 + ko + kk + quad * 8;
      float4 x0 = *(const float4*)xp;
      float4 x1 = *(const float4*)(xp + 4);
      b8v a;
      a[0] = (__bf16)x0.x; a[1] = (__bf16)x0.y; a[2] = (__bf16)x0.z; a[3] = (__bf16)x0.w;
      a[4] = (__bf16)x1.x; a[5] = (__bf16)x1.y; a[6] = (__bf16)x1.z; a[7] = (__bf16)x1.w;
#pragma unroll
      for (int ct = 0; ct < 16; ++ct) {
        b8v bf = *(const b8v*)&Ws[ct * 16 + lrow][kk + quad * 8];
        acc[ct] = MFMA_BF16(a, bf, acc[ct]);
      }
    }
    __syncthreads();
    if (kc == 448) {  // phase 1 (qc+qp) complete -> write half 0
#pragma unroll
      for (int ct = 0; ct < 16; ++ct) {
        int col = ct * 16 + lrow;
        float bsum = b_qc[col] + b_qp[col];
        int h = col >> 5, d = col & 31;
#pragma unroll
        for (int r = 0; r < 4; ++r) {
          int row = r0 + wave * 16 + quad * 4 + r;
          int n = row >> 4, bb = row & 15;
          Q64[((size_t)(bb * 8 + h) * 320 + n) * 64 + d] = (__bf16)((acc[ct][r] + bsum) * 0.125f);
        }
      }
    }
  }
  // phase 2 complete -> write half 1 (q1 + qs)
#pragma unroll
  for (int ct = 0; ct < 16; ++ct) {
    int col = ct * 16 + lrow;
    float bsum = b_qc[col] + b_qp[col] + b_qs[col];
    int h = col >> 5, d = col & 31;
#pragma unroll
    for (int r = 0; r < 4; ++r) {
      int row = r0 + wave * 16 + quad * 4 + r;
      int n = row >> 4, bb = row & 15;
      Q64[((size_t)(bb * 8 + h) * 320 + n) * 64 + 32 + d] = (__bf16)((acc[ct][r] + bsum) * 0.125f);
    }
  }
}

// ---------------------------------------------------------------------------
// Kernel C: flash attention. Grid (5 q-tiles of 64, 128 bh). 4 waves x 16 q-rows.
// L-chunks of 128. P round-trips LDS with an l-permutation pi(l)=(l&15)*8+(l>>4)
// applied to BOTH P and V^T columns so P stores are ds_write_b128.
__global__ __launch_bounds__(256) void attn_kernel(
    const __bf16* __restrict__ Q64, const __bf16* __restrict__ K64,
    const __bf16* __restrict__ V32, __bf16* __restrict__ Obf)
{
  __shared__ __bf16 Ks[128][72];
  __shared__ __bf16 Vt[32][136];   // [d][pi(l)]
  __shared__ __bf16 Ps[64][136];   // [q][pi(l)]
  const int tid  = threadIdx.x;
  const int wave = tid >> 6, lane = tid & 63;
  const int lrow = lane & 15, quad = lane >> 4;
  const int bh = blockIdx.y;             // b*8 + h
  const int n0 = blockIdx.x * 64;

  // Q fragments straight from global (read once per block)
  const __bf16* Qb = Q64 + ((size_t)bh * 320 + n0 + wave * 16 + lrow) * 64;
  const b8v qa0 = *(const b8v*)(Qb + quad * 8);
  const b8v qa1 = *(const b8v*)(Qb + 32 + quad * 8);

  const __bf16* Kb = K64 + (size_t)bh * 4096 * 64;
  const __bf16* Vb = V32 + (size_t)bh * 4096 * 32;

  float mst[4], lst[4];
#pragma unroll
  for (int i = 0; i < 4; ++i) { mst[i] = -1e30f; lst[i] = 0.f; }
  f4 oacc[2];
  oacc[0] = f4{0.f, 0.f, 0.f, 0.f};
  oacc[1] = f4{0.f, 0.f, 0.f, 0.f};

  for (int l0 = 0; l0 < 4096; l0 += 128) {
    // stage K chunk [128][64]
#pragma unroll
    for (int it = 0; it < 4; ++it) {
      int idx = it * 256 + tid;
      int row = idx >> 3, s = idx & 7;
      *(uint4*)&Ks[row][s * 8] = *(const uint4*)(Kb + (size_t)(l0 + row) * 64 + s * 8);
    }
    // stage V chunk transposed + pi-permuted: Vt[d][pi(l)]
#pragma unroll
    for (int it = 0; it < 2; ++it) {
      int idx = it * 256 + tid;
      int row = idx >> 2, s = idx & 3;   // row = l_local, s: d-octet
      uint4 u = *(const uint4*)(Vb + (size_t)(l0 + row) * 32 + s * 8);
      __bf16 tmp[8]; *(uint4*)tmp = u;
      int pc = ((row & 15) << 3) | (row >> 4);
#pragma unroll
      for (int j = 0; j < 8; ++j) Vt[s * 8 + j][pc] = tmp[j];
    }
    __syncthreads();

    // S = Q K^T  (wave rows [wave*16,+16), cols 128)
    f4 sc[8];
#pragma unroll
    for (int ct = 0; ct < 8; ++ct) {
      b8v kb0 = *(const b8v*)&Ks[ct * 16 + lrow][quad * 8];
      b8v kb1 = *(const b8v*)&Ks[ct * 16 + lrow][32 + quad * 8];
      f4 z = f4{0.f, 0.f, 0.f, 0.f};
      z = MFMA_BF16(qa0, kb0, z);
      z = MFMA_BF16(qa1, kb1, z);
      sc[ct] = z;
    }

    // online softmax (row = quad*4 + r; reduce over 16 lanes of the quad)
    float rmax[4], rsum[4], alpha[4];
#pragma unroll
    for (int r = 0; r < 4; ++r) {
      float v = sc[0][r];
#pragma unroll
      for (int ct = 1; ct < 8; ++ct) v = fmaxf(v, sc[ct][r]);
      rmax[r] = v;
    }
#pragma unroll
    for (int off = 8; off >= 1; off >>= 1)
#pragma unroll
      for (int r = 0; r < 4; ++r)
        rmax[r] = fmaxf(rmax[r], __shfl_xor(rmax[r], off, 16));
#pragma unroll
    for (int r = 0; r < 4; ++r) {
      float mnew = fmaxf(mst[r], rmax[r]);
      alpha[r] = __expf(mst[r] - mnew);
      mst[r] = mnew;
    }
#pragma unroll
    for (int ct = 0; ct < 8; ++ct)
#pragma unroll
      for (int r = 0; r < 4; ++r)
        sc[ct][r] = __expf(sc[ct][r] - mst[r]);
#pragma unroll
    for (int r = 0; r < 4; ++r) {
      float v = sc[0][r];
#pragma unroll
      for (int ct = 1; ct < 8; ++ct) v += sc[ct][r];
      rsum[r] = v;
    }
#pragma unroll
    for (int off = 8; off >= 1; off >>= 1)
#pragma unroll
      for (int r = 0; r < 4; ++r)
        rsum[r] += __shfl_xor(rsum[r], off, 16);
#pragma unroll
    for (int r = 0; r < 4; ++r) lst[r] = lst[r] * alpha[r] + rsum[r];
#pragma unroll
    for (int c2 = 0; c2 < 2; ++c2)
#pragma unroll
      for (int r = 0; r < 4; ++r) oacc[c2][r] *= alpha[r];

    // P -> LDS in A-operand-friendly pi layout: lane's 8 ct-values are contiguous
#pragma unroll
    for (int r = 0; r < 4; ++r) {
      b8v pv;
#pragma unroll
      for (int ct = 0; ct < 8; ++ct) pv[ct] = (__bf16)sc[ct][r];
      *(b8v*)&Ps[wave * 16 + quad * 4 + r][lrow * 8] = pv;
    }

    // O += P V (contraction over pi-space, consistent for P and Vt)
#pragma unroll
    for (int kt = 0; kt < 4; ++kt) {
      b8v pa = *(const b8v*)&Ps[wave * 16 + lrow][kt * 32 + quad * 8];
#pragma unroll
      for (int c2 = 0; c2 < 2; ++c2) {
        b8v vb = *(const b8v*)&Vt[c2 * 16 + lrow][kt * 32 + quad * 8];
        oacc[c2] = MFMA_BF16(pa, vb, oacc[c2]);
      }
    }
    __syncthreads();
  }

  // epilogue: normalize, write Obf[b][n][h*32+d] bf16
  const int bb = bh >> 3, h = bh & 7;
#pragma unroll
  for (int r = 0; r < 4; ++r) {
    int n = n0 + wave * 16 + quad * 4 + r;
    if (n < 300) {
      float inv = 1.0f / lst[r];
#pragma unroll
      for (int c2 = 0; c2 < 2; ++c2) {
        int col = h * 32 + c2 * 16 + lrow;
        Obf[((size_t)bb * 300 + n) * 256 + col] = (__bf16)(oacc[c2][r] * inv);
      }
    }
  }
}

// ---------------------------------------------------------------------------
// Kernel D: out = identity + Obf @ W_o^T + b_o.  M = 4800 (row = b*300+n), BM=64.
__global__ __launch_bounds__(256) void out_proj_gemm(
    const __bf16* __restrict__ Obf, const float* __restrict__ W_o,
    const float* __restrict__ b_o, const float* __restrict__ query,
    float* __restrict__ out)
{
  __shared__ __bf16 Ws[256][72];
  const int tid  = threadIdx.x;
  const int wave = tid >> 6, lane = tid & 63;
  const int lrow = lane & 15, quad = lane >> 4;
  const int r0 = blockIdx.x * 64;

  f4 acc[16];
#pragma unroll
  for (int i = 0; i < 16; ++i) acc[i] = f4{0.f, 0.f, 0.f, 0.f};

  for (int kc0 = 0; kc0 < 256; kc0 += 64) {
#pragma unroll
    for (int it = 0; it < 16; ++it) {
      int idx = it * 256 + tid;
      int row = idx >> 4, c4 = idx & 15;
      float4 w = *(const float4*)(W_o + (size_t)row * 256 + kc0 + c4 * 4);
      __bf16* dp = &Ws[row][c4 * 4];
      dp[0] = (__bf16)w.x; dp[1] = (__bf16)w.y; dp[2] = (__bf16)w.z; dp[3] = (__bf16)w.w;
    }
    __syncthreads();
#pragma unroll
    for (int kk = 0; kk < 64; kk += 32) {
      b8v a = *(const b8v*)(Obf + (size_t)(r0 + wave * 16 + lrow) * 256 + kc0 + kk + quad * 8);
#pragma unroll
      for (int ct = 0; ct < 16; ++ct) {
        b8v bf = *(const b8v*)&Ws[ct * 16 + lrow][kk + quad * 8];
        acc[ct] = MFMA_BF16(a, bf, acc[ct]);
      }
    }
    __syncthreads();
  }
#pragma unroll
  for (int ct = 0; ct < 16; ++ct) {
    int col = ct * 16 + lrow;
    float bo = b_o[col];
#pragma unroll
    for (int r = 0; r < 4; ++r) {
      int row = r0 + wave * 16 + quad * 4 + r;
      int bb = row / 300, n = row % 300;
      size_t oaddr = ((size_t)n * 16 + bb) * 256 + col;
      out[oaddr] = acc[ct][r] + bo + query[oaddr];
    }
  }
}

// ---------------------------------------------------------------------------
extern "C" void kernel_launch(void* const* d_in, const int* in_sizes, int n_in,
                              void* d_out, int out_size, void* d_ws, size_t ws_size,
                              hipStream_t stream) {
  (void)in_sizes; (void)n_in; (void)out_size; (void)ws_size;
  const float* query      = (const float*)d_in[0];
  const float* key        = (const float*)d_in[1];
  const float* value      = (const float*)d_in[2];
  const float* query_pos  = (const float*)d_in[3];
  const float* key_pos    = (const float*)d_in[4];
  const float* query_sine = (const float*)d_in[5];
  const float* W_qc = (const float*)d_in[6];  const float* b_qc = (const float*)d_in[7];
  const float* W_qp = (const float*)d_in[8];  const float* b_qp = (const float*)d_in[9];
  const float* W_qs = (const float*)d_in[10]; const float* b_qs = (const float*)d_in[11];
  const float* W_kc = (const float*)d_in[12]; const float* b_kc = (const float*)d_in[13];
  const float* W_kp = (const float*)d_in[14]; const float* b_kp = (const float*)d_in[15];
  const float* W_v  = (const float*)d_in[16]; const float* b_v  = (const float*)d_in[17];
  const float* W_o  = (const float*)d_in[18]; const float* b_o  = (const float*)d_in[19];
  float* out = (float*)d_out;

  char* ws = (char*)d_ws;
  constexpr size_t K64_BYTES = (size_t)128 * 4096 * 64 * 2;  // 64 MiB
  constexpr size_t V32_BYTES = (size_t)128 * 4096 * 32 * 2;  // 32 MiB
  constexpr size_t Q64_BYTES = (size_t)128 * 320 * 64 * 2;   //  5 MiB
  __bf16* K64 = (__bf16*)ws;
  __bf16* V32 = (__bf16*)(ws + K64_BYTES);
  __bf16* Q64 = (__bf16*)(ws + K64_BYTES + V32_BYTES);
  __bf16* Obf = (__bf16*)(ws + K64_BYTES + V32_BYTES + Q64_BYTES);

  hipLaunchKernelGGL(key_side_gemm, dim3(2, 256), dim3(256), 0, stream,
                     key, key_pos, value, W_kc, b_kc, W_kp, b_kp, W_v, b_v, K64, V32);
  hipLaunchKernelGGL(query_side_gemm, dim3(75), dim3(256), 0, stream,
                     query, query_pos, query_sine, W_qc, b_qc, W_qp, b_qp, W_qs, b_qs, Q64);
  hipLaunchKernelGGL(attn_kernel, dim3(5, 128), dim3(256), 0, stream,
                     Q64, K64, V32, Obf);
  hipLaunchKernelGGL(out_proj_gemm, dim3(75), dim3(256), 0, stream,
                     Obf, W_o, b_o, query, out);
}

// Round 2
// 495.172 us; speedup vs baseline: 1.3626x; 1.3626x over previous
//
#include <hip/hip_runtime.h>
#include <cstdint>
#include <cstddef>

// MI355X / gfx950. bf16 MFMA implementation of ConditionalCrossAttention.
// score = (qc+qp)|(qc+qp+qs)  dot  kc|kp   (algebraic refold of the concat heads)
// ws layout: K64[128][4096][64] bf16 | V32[128][4096][32] bf16 |
//            Q64[128][320][64] bf16  | Obf[16][300][256] bf16 | Wbf[3][256][256] bf16

typedef float  f4  __attribute__((ext_vector_type(4)));
typedef __bf16 b8v __attribute__((ext_vector_type(8)));

#define MFMA_BF16(a, b, c) __builtin_amdgcn_mfma_f32_16x16x32_bf16((a), (b), (c), 0, 0, 0)

#define GLD_LDS16(gp, lp)                                             \
  __builtin_amdgcn_global_load_lds(                                   \
      (const __attribute__((address_space(1))) void*)(gp),            \
      (__attribute__((address_space(3))) void*)(lp), 16, 0, 0)

// ---------------------------------------------------------------------------
// Prepass: convert key-side weights fp32 -> bf16 (W_kc, W_kp, W_v -> Wbf[3][256*256])
__global__ __launch_bounds__(256) void convert_w(
    const float* __restrict__ W0, const float* __restrict__ W1,
    const float* __restrict__ W2, __bf16* __restrict__ Wbf)
{
  int i = blockIdx.x * 256 + threadIdx.x;      // 0 .. 49151
  int base = i * 4;                            // elem index, 4 per thread
  int m = base >> 16;                          // which matrix
  int off = base & 65535;
  const float* W = (m == 0) ? W0 : (m == 1) ? W1 : W2;
  float4 v = *(const float4*)(W + off);
  __bf16 o[4];
  o[0] = (__bf16)v.x; o[1] = (__bf16)v.y; o[2] = (__bf16)v.z; o[3] = (__bf16)v.w;
  *(uint2*)(Wbf + (size_t)m * 65536 + off) = *(uint2*)o;
}

// ---------------------------------------------------------------------------
// Kernel A v2: key-side linears, m97-style.
// Grid (512, 3): blockIdx.x = M-tile of 128 rows (M = L*B = 65536, row = l*16+b),
// blockIdx.y = p in {kc, kp, v}. BN = 256 (full width) so X is fetched exactly once.
// W (pre-converted bf16) staged via global_load_lds, double-buffered, BK=64,
// xor-swizzled granules (g ^= row&7) for conflict-free ds_read_b128.
// A fragments: global->VGPR fp32, software-pipelined one kk-phase ahead, cvt->bf16.
// Epilogue: acc -> LDS tile -> full-64B-line coalesced 16B/lane stores.
__global__ __launch_bounds__(256, 2) void key_side_gemm(
    const float* __restrict__ key, const float* __restrict__ key_pos,
    const float* __restrict__ value, const __bf16* __restrict__ Wbf,
    const float* __restrict__ b_kc, const float* __restrict__ b_kp,
    const float* __restrict__ b_v,
    __bf16* __restrict__ K64, __bf16* __restrict__ V32)
{
  __shared__ char smem[65536];   // 2 x 32KB W dbuf; reused as 64KB output tile
  const int tid  = threadIdx.x;
  const int wave = tid >> 6, lane = tid & 63;
  const int lrow = lane & 15, quad = lane >> 4;
  const int p  = blockIdx.y;
  const int r0 = blockIdx.x * 128;
  const int rowbase = (wave & 1) * 64;     // 2x2 wave grid: 64 rows x 128 cols each
  const int colbase = (wave >> 1) * 128;

  const float* __restrict__ X = (p == 0) ? key : (p == 1) ? key_pos : value;
  const __bf16* __restrict__ Wb = Wbf + (size_t)p * 65536;
  const float* __restrict__ bias = (p == 0) ? b_kc : (p == 1) ? b_kp : b_v;

  // ---- helpers ----
  // stage W[0:256][kc:kc+64) bf16 into buf, granule-swizzled: slot(wr,gp) <- g = gp^(wr&7)
  auto stageW = [&](int buf, int kc) {
#pragma unroll
    for (int it = 0; it < 8; ++it) {
      int slot = it * 256 + tid;            // 2048 granules of 16B
      int wr = slot >> 3, gp = slot & 7;
      int g  = gp ^ (wr & 7);
      GLD_LDS16(Wb + (size_t)wr * 256 + kc + g * 8, smem + buf * 32768 + slot * 16);
    }
  };
  auto readB = [&](int buf, int ct, int kk4) -> b8v {   // kk4 = kk/8 (0 or 4)
    int wr = colbase + ct * 16 + lrow;
    int g  = (kk4 + quad) ^ (wr & 7);
    return *(const b8v*)(smem + buf * 32768 + wr * 128 + g * 16);
  };
  auto loadA = [&](float4* x0, float4* x1, int kc) {
#pragma unroll
    for (int rt = 0; rt < 4; ++rt) {
      const float* xp = X + (size_t)(r0 + rowbase + rt * 16 + lrow) * 256 + kc + quad * 8;
      x0[rt] = *(const float4*)xp;
      x1[rt] = *(const float4*)(xp + 4);
    }
  };
  auto mk = [&](float4 x0, float4 x1) -> b8v {
    b8v t;
    t[0] = (__bf16)x0.x; t[1] = (__bf16)x0.y; t[2] = (__bf16)x0.z; t[3] = (__bf16)x0.w;
    t[4] = (__bf16)x1.x; t[5] = (__bf16)x1.y; t[6] = (__bf16)x1.z; t[7] = (__bf16)x1.w;
    return t;
  };

  f4 acc[4][8];
#pragma unroll
  for (int i = 0; i < 4; ++i)
#pragma unroll
    for (int j = 0; j < 8; ++j) acc[i][j] = f4{0.f, 0.f, 0.f, 0.f};

  float4 c0[4], c1[4], d0[4], d1[4];
  loadA(c0, c1, 0);          // A for s=0, kk=0
  stageW(0, 0);
  __syncthreads();           // drains vmcnt(0): buf0 + c ready

  for (int s = 0; s < 4; ++s) {
    const int kc0 = s * 64, buf = s & 1;
    loadA(d0, d1, kc0 + 32);            // A for kk=32 (issued first: oldest in vmcnt)
    if (s < 3) stageW(buf ^ 1, kc0 + 64);

    // compute kk = 0 (c regs are complete: drained at previous barrier)
    b8v a[4];
#pragma unroll
    for (int rt = 0; rt < 4; ++rt) a[rt] = mk(c0[rt], c1[rt]);
#pragma unroll
    for (int ct = 0; ct < 8; ++ct) {
      b8v bfr = readB(buf, ct, 0);
#pragma unroll
      for (int rt = 0; rt < 4; ++rt) acc[rt][ct] = MFMA_BF16(a[rt], bfr, acc[rt][ct]);
    }

    if (s < 3) loadA(c0, c1, kc0 + 64); // A for next step kk=0 (drained at barrier)

    // compute kk = 32
#pragma unroll
    for (int rt = 0; rt < 4; ++rt) a[rt] = mk(d0[rt], d1[rt]);
#pragma unroll
    for (int ct = 0; ct < 8; ++ct) {
      b8v bfr = readB(buf, ct, 4);
#pragma unroll
      for (int rt = 0; rt < 4; ++rt) acc[rt][ct] = MFMA_BF16(a[rt], bfr, acc[rt][ct]);
    }
    __syncthreads();
  }

  // ---- epilogue: acc -> LDS [128][256] bf16 -> coalesced 64B-line stores ----
  __bf16* Os = (__bf16*)smem;
#pragma unroll
  for (int ct = 0; ct < 8; ++ct) {
    int col = colbase + ct * 16 + lrow;
    float bv = bias[col];
#pragma unroll
    for (int rt = 0; rt < 4; ++rt)
#pragma unroll
      for (int r = 0; r < 4; ++r) {
        int row = rowbase + rt * 16 + quad * 4 + r;
        Os[row * 256 + col] = (__bf16)(acc[rt][ct][r] + bv);
      }
  }
  __syncthreads();
  // 1024 chunks of 64B (chunk = row*8 + h); lane handles chunk (lane&15), 16B quarter (lane>>4)
#pragma unroll
  for (int it = 0; it < 16; ++it) {
    int chunk = it * 64 + wave * 16 + (lane & 15);
    int q = lane >> 4;
    int row = chunk >> 3, h = chunk & 7;
    int R = r0 + row, l = R >> 4, bb = R & 15;
    uint4 v = *(const uint4*)(Os + chunk * 32 + q * 8);
    __bf16* dst = (p == 2) ? (V32 + ((size_t)(bb * 8 + h) * 4096 + l) * 32)
                           : (K64 + ((size_t)(bb * 8 + h) * 4096 + l) * 64 + p * 32);
    *(uint4*)(dst + q * 8) = v;
  }
}

// ---------------------------------------------------------------------------
// Kernel B: query-side. One accumulator, phased:
//   phase 1 (K=512 concat): T = query@W_qc^T + query_pos@W_qp^T  -> write half 0 (T+biases)*scale
//   phase 2 (K=256):        T += query_sine@W_qs^T               -> write half 1 (T+biases)*scale
// M = 4800 (row = n*16+b), BM=64, BN=256, scale = 1/8 folded into Q.
__global__ __launch_bounds__(256) void query_side_gemm(
    const float* __restrict__ query, const float* __restrict__ query_pos,
    const float* __restrict__ query_sine,
    const float* __restrict__ W_qc, const float* __restrict__ b_qc,
    const float* __restrict__ W_qp, const float* __restrict__ b_qp,
    const float* __restrict__ W_qs, const float* __restrict__ b_qs,
    __bf16* __restrict__ Q64)
{
  __shared__ __bf16 Ws[256][72];
  const int tid  = threadIdx.x;
  const int wave = tid >> 6, lane = tid & 63;
  const int lrow = lane & 15, quad = lane >> 4;
  const int r0 = blockIdx.x * 64;

  f4 acc[16];
#pragma unroll
  for (int i = 0; i < 16; ++i) acc[i] = f4{0.f, 0.f, 0.f, 0.f};

  for (int kc = 0; kc < 768; kc += 64) {
    const float* X; const float* W;
    if (kc < 256)      { X = query;      W = W_qc; }
    else if (kc < 512) { X = query_pos;  W = W_qp; }
    else               { X = query_sine; W = W_qs; }
    const int ko = kc & 255;
#pragma unroll
    for (int it = 0; it < 16; ++it) {
      int idx = it * 256 + tid;
      int row = idx >> 4, c4 = idx & 15;
      float4 w = *(const float4*)(W + (size_t)row * 256 + ko + c4 * 4);
      __bf16* dp = &Ws[row][c4 * 4];
      dp[0] = (__bf16)w.x; dp[1] = (__bf16)w.y; dp[2] = (__bf16)w.z; dp[3] = (__bf16)w.w;
    }
    __syncthreads();
#pragma unroll
    for (int kk = 0; kk < 64; kk += 32) {
      const float* xp = X + (size_t)(r0 + wave * 16 + lrow) * 256 + ko + kk + quad * 8;
      float4 x0 = *(const float4*)xp;
      float4 x1 = *(const float4*)(xp + 4);
      b8v a;
      a[0] = (__bf16)x0.x; a[1] = (__bf16)x0.y; a[2] = (__bf16)x0.z; a[3] = (__bf16)x0.w;
      a[4] = (__bf16)x1.x; a[5] = (__bf16)x1.y; a[6] = (__bf16)x1.z; a[7] = (__bf16)x1.w;
#pragma unroll
      for (int ct = 0; ct < 16; ++ct) {
        b8v bf = *(const b8v*)&Ws[ct * 16 + lrow][kk + quad * 8];
        acc[ct] = MFMA_BF16(a, bf, acc[ct]);
      }
    }
    __syncthreads();
    if (kc == 448) {  // phase 1 (qc+qp) complete -> write half 0
#pragma unroll
      for (int ct = 0; ct < 16; ++ct) {
        int col = ct * 16 + lrow;
        float bsum = b_qc[col] + b_qp[col];
        int h = col >> 5, d = col & 31;
#pragma unroll
        for (int r = 0; r < 4; ++r) {
          int row = r0 + wave * 16 + quad * 4 + r;
          int n = row >> 4, bb = row & 15;
          Q64[((size_t)(bb * 8 + h) * 320 + n) * 64 + d] = (__bf16)((acc[ct][r] + bsum) * 0.125f);
        }
      }
    }
  }
  // phase 2 complete -> write half 1 (q1 + qs)
#pragma unroll
  for (int ct = 0; ct < 16; ++ct) {
    int col = ct * 16 + lrow;
    float bsum = b_qc[col] + b_qp[col] + b_qs[col];
    int h = col >> 5, d = col & 31;
#pragma unroll
    for (int r = 0; r < 4; ++r) {
      int row = r0 + wave * 16 + quad * 4 + r;
      int n = row >> 4, bb = row & 15;
      Q64[((size_t)(bb * 8 + h) * 320 + n) * 64 + 32 + d] = (__bf16)((acc[ct][r] + bsum) * 0.125f);
    }
  }
}

// ---------------------------------------------------------------------------
// Kernel C: flash attention. Grid (5 q-tiles of 64, 128 bh). 4 waves x 16 q-rows.
// L-chunks of 128. P round-trips LDS with an l-permutation pi(l)=(l&15)*8+(l>>4)
// applied to BOTH P and V^T columns so P stores are ds_write_b128.
__global__ __launch_bounds__(256) void attn_kernel(
    const __bf16* __restrict__ Q64, const __bf16* __restrict__ K64,
    const __bf16* __restrict__ V32, __bf16* __restrict__ Obf)
{
  __shared__ __bf16 Ks[128][72];
  __shared__ __bf16 Vt[32][136];   // [d][pi(l)]
  __shared__ __bf16 Ps[64][136];   // [q][pi(l)]
  const int tid  = threadIdx.x;
  const int wave = tid >> 6, lane = tid & 63;
  const int lrow = lane & 15, quad = lane >> 4;
  const int bh = blockIdx.y;             // b*8 + h
  const int n0 = blockIdx.x * 64;

  // Q fragments straight from global (read once per block)
  const __bf16* Qb = Q64 + ((size_t)bh * 320 + n0 + wave * 16 + lrow) * 64;
  const b8v qa0 = *(const b8v*)(Qb + quad * 8);
  const b8v qa1 = *(const b8v*)(Qb + 32 + quad * 8);

  const __bf16* Kb = K64 + (size_t)bh * 4096 * 64;
  const __bf16* Vb = V32 + (size_t)bh * 4096 * 32;

  float mst[4], lst[4];
#pragma unroll
  for (int i = 0; i < 4; ++i) { mst[i] = -1e30f; lst[i] = 0.f; }
  f4 oacc[2];
  oacc[0] = f4{0.f, 0.f, 0.f, 0.f};
  oacc[1] = f4{0.f, 0.f, 0.f, 0.f};

  for (int l0 = 0; l0 < 4096; l0 += 128) {
    // stage K chunk [128][64]
#pragma unroll
    for (int it = 0; it < 4; ++it) {
      int idx = it * 256 + tid;
      int row = idx >> 3, s = idx & 7;
      *(uint4*)&Ks[row][s * 8] = *(const uint4*)(Kb + (size_t)(l0 + row) * 64 + s * 8);
    }
    // stage V chunk transposed + pi-permuted: Vt[d][pi(l)]
#pragma unroll
    for (int it = 0; it < 2; ++it) {
      int idx = it * 256 + tid;
      int row = idx >> 2, s = idx & 3;   // row = l_local, s: d-octet
      uint4 u = *(const uint4*)(Vb + (size_t)(l0 + row) * 32 + s * 8);
      __bf16 tmp[8]; *(uint4*)tmp = u;
      int pc = ((row & 15) << 3) | (row >> 4);
#pragma unroll
      for (int j = 0; j < 8; ++j) Vt[s * 8 + j][pc] = tmp[j];
    }
    __syncthreads();

    // S = Q K^T  (wave rows [wave*16,+16), cols 128)
    f4 sc[8];
#pragma unroll
    for (int ct = 0; ct < 8; ++ct) {
      b8v kb0 = *(const b8v*)&Ks[ct * 16 + lrow][quad * 8];
      b8v kb1 = *(const b8v*)&Ks[ct * 16 + lrow][32 + quad * 8];
      f4 z = f4{0.f, 0.f, 0.f, 0.f};
      z = MFMA_BF16(qa0, kb0, z);
      z = MFMA_BF16(qa1, kb1, z);
      sc[ct] = z;
    }

    // online softmax (row = quad*4 + r; reduce over 16 lanes of the quad)
    float rmax[4], rsum[4], alpha[4];
#pragma unroll
    for (int r = 0; r < 4; ++r) {
      float v = sc[0][r];
#pragma unroll
      for (int ct = 1; ct < 8; ++ct) v = fmaxf(v, sc[ct][r]);
      rmax[r] = v;
    }
#pragma unroll
    for (int off = 8; off >= 1; off >>= 1)
#pragma unroll
      for (int r = 0; r < 4; ++r)
        rmax[r] = fmaxf(rmax[r], __shfl_xor(rmax[r], off, 16));
#pragma unroll
    for (int r = 0; r < 4; ++r) {
      float mnew = fmaxf(mst[r], rmax[r]);
      alpha[r] = __expf(mst[r] - mnew);
      mst[r] = mnew;
    }
#pragma unroll
    for (int ct = 0; ct < 8; ++ct)
#pragma unroll
      for (int r = 0; r < 4; ++r)
        sc[ct][r] = __expf(sc[ct][r] - mst[r]);
#pragma unroll
    for (int r = 0; r < 4; ++r) {
      float v = sc[0][r];
#pragma unroll
      for (int ct = 1; ct < 8; ++ct) v += sc[ct][r];
      rsum[r] = v;
    }
#pragma unroll
    for (int off = 8; off >= 1; off >>= 1)
#pragma unroll
      for (int r = 0; r < 4; ++r)
        rsum[r] += __shfl_xor(rsum[r], off, 16);
#pragma unroll
    for (int r = 0; r < 4; ++r) lst[r] = lst[r] * alpha[r] + rsum[r];
#pragma unroll
    for (int c2 = 0; c2 < 2; ++c2)
#pragma unroll
      for (int r = 0; r < 4; ++r) oacc[c2][r] *= alpha[r];

    // P -> LDS in A-operand-friendly pi layout: lane's 8 ct-values are contiguous
#pragma unroll
    for (int r = 0; r < 4; ++r) {
      b8v pv;
#pragma unroll
      for (int ct = 0; ct < 8; ++ct) pv[ct] = (__bf16)sc[ct][r];
      *(b8v*)&Ps[wave * 16 + quad * 4 + r][lrow * 8] = pv;
    }

    // O += P V (contraction over pi-space, consistent for P and Vt)
#pragma unroll
    for (int kt = 0; kt < 4; ++kt) {
      b8v pa = *(const b8v*)&Ps[wave * 16 + lrow][kt * 32 + quad * 8];
#pragma unroll
      for (int c2 = 0; c2 < 2; ++c2) {
        b8v vb = *(const b8v*)&Vt[c2 * 16 + lrow][kt * 32 + quad * 8];
        oacc[c2] = MFMA_BF16(pa, vb, oacc[c2]);
      }
    }
    __syncthreads();
  }

  // epilogue: normalize, write Obf[b][n][h*32+d] bf16
  const int bb = bh >> 3, h = bh & 7;
#pragma unroll
  for (int r = 0; r < 4; ++r) {
    int n = n0 + wave * 16 + quad * 4 + r;
    if (n < 300) {
      float inv = 1.0f / lst[r];
#pragma unroll
      for (int c2 = 0; c2 < 2; ++c2) {
        int col = h * 32 + c2 * 16 + lrow;
        Obf[((size_t)bb * 300 + n) * 256 + col] = (__bf16)(oacc[c2][r] * inv);
      }
    }
  }
}

// ---------------------------------------------------------------------------
// Kernel D: out = identity + Obf @ W_o^T + b_o.  M = 4800 (row = b*300+n), BM=64.
__global__ __launch_bounds__(256) void out_proj_gemm(
    const __bf16* __restrict__ Obf, const float* __restrict__ W_o,
    const float* __restrict__ b_o, const float* __restrict__ query,
    float* __restrict__ out)
{
  __shared__ __bf16 Ws[256][72];
  const int tid  = threadIdx.x;
  const int wave = tid >> 6, lane = tid & 63;
  const int lrow = lane & 15, quad = lane >> 4;
  const int r0 = blockIdx.x * 64;

  f4 acc[16];
#pragma unroll
  for (int i = 0; i < 16; ++i) acc[i] = f4{0.f, 0.f, 0.f, 0.f};

  for (int kc0 = 0; kc0 < 256; kc0 += 64) {
#pragma unroll
    for (int it = 0; it < 16; ++it) {
      int idx = it * 256 + tid;
      int row = idx >> 4, c4 = idx & 15;
      float4 w = *(const float4*)(W_o + (size_t)row * 256 + kc0 + c4 * 4);
      __bf16* dp = &Ws[row][c4 * 4];
      dp[0] = (__bf16)w.x; dp[1] = (__bf16)w.y; dp[2] = (__bf16)w.z; dp[3] = (__bf16)w.w;
    }
    __syncthreads();
#pragma unroll
    for (int kk = 0; kk < 64; kk += 32) {
      b8v a = *(const b8v*)(Obf + (size_t)(r0 + wave * 16 + lrow) * 256 + kc0 + kk + quad * 8);
#pragma unroll
      for (int ct = 0; ct < 16; ++ct) {
        b8v bf = *(const b8v*)&Ws[ct * 16 + lrow][kk + quad * 8];
        acc[ct] = MFMA_BF16(a, bf, acc[ct]);
      }
    }
    __syncthreads();
  }
#pragma unroll
  for (int ct = 0; ct < 16; ++ct) {
    int col = ct * 16 + lrow;
    float bo = b_o[col];
#pragma unroll
    for (int r = 0; r < 4; ++r) {
      int row = r0 + wave * 16 + quad * 4 + r;
      int bb = row / 300, n = row % 300;
      size_t oaddr = ((size_t)n * 16 + bb) * 256 + col;
      out[oaddr] = acc[ct][r] + bo + query[oaddr];
    }
  }
}

// ---------------------------------------------------------------------------
extern "C" void kernel_launch(void* const* d_in, const int* in_sizes, int n_in,
                              void* d_out, int out_size, void* d_ws, size_t ws_size,
                              hipStream_t stream) {
  (void)in_sizes; (void)n_in; (void)out_size; (void)ws_size;
  const float* query      = (const float*)d_in[0];
  const float* key        = (const float*)d_in[1];
  const float* value      = (const float*)d_in[2];
  const float* query_pos  = (const float*)d_in[3];
  const float* key_pos    = (const float*)d_in[4];
  const float* query_sine = (const float*)d_in[5];
  const float* W_qc = (const float*)d_in[6];  const float* b_qc = (const float*)d_in[7];
  const float* W_qp = (const float*)d_in[8];  const float* b_qp = (const float*)d_in[9];
  const float* W_qs = (const float*)d_in[10]; const float* b_qs = (const float*)d_in[11];
  const float* W_kc = (const float*)d_in[12]; const float* b_kc = (const float*)d_in[13];
  const float* W_kp = (const float*)d_in[14]; const float* b_kp = (const float*)d_in[15];
  const float* W_v  = (const float*)d_in[16]; const float* b_v  = (const float*)d_in[17];
  const float* W_o  = (const float*)d_in[18]; const float* b_o  = (const float*)d_in[19];
  float* out = (float*)d_out;

  char* ws = (char*)d_ws;
  constexpr size_t K64_BYTES = (size_t)128 * 4096 * 64 * 2;  // 64 MiB
  constexpr size_t V32_BYTES = (size_t)128 * 4096 * 32 * 2;  // 32 MiB
  constexpr size_t Q64_BYTES = (size_t)128 * 320 * 64 * 2;   //  5 MiB
  constexpr size_t OBF_BYTES = (size_t)16 * 300 * 256 * 2;   //  2.34 MiB
  __bf16* K64 = (__bf16*)ws;
  __bf16* V32 = (__bf16*)(ws + K64_BYTES);
  __bf16* Q64 = (__bf16*)(ws + K64_BYTES + V32_BYTES);
  __bf16* Obf = (__bf16*)(ws + K64_BYTES + V32_BYTES + Q64_BYTES);
  __bf16* Wbf = (__bf16*)(ws + K64_BYTES + V32_BYTES + Q64_BYTES + OBF_BYTES);

  hipLaunchKernelGGL(convert_w, dim3(192), dim3(256), 0, stream,
                     W_kc, W_kp, W_v, Wbf);
  hipLaunchKernelGGL(key_side_gemm, dim3(512, 3), dim3(256), 0, stream,
                     key, key_pos, value, Wbf, b_kc, b_kp, b_v, K64, V32);
  hipLaunchKernelGGL(query_side_gemm, dim3(75), dim3(256), 0, stream,
                     query, query_pos, query_sine, W_qc, b_qc, W_qp, b_qp, W_qs, b_qs, Q64);
  hipLaunchKernelGGL(attn_kernel, dim3(5, 128), dim3(256), 0, stream,
                     Q64, K64, V32, Obf);
  hipLaunchKernelGGL(out_proj_gemm, dim3(75), dim3(256), 0, stream,
                     Obf, W_o, b_o, query, out);
}